// Round 3
// baseline (153.473 us; speedup 1.0000x reference)
//
#include <hip/hip_runtime.h>
#include <hip/hip_bf16.h>

// Single fused kernel. 256 blocks x 256 threads; wave w owns rows
// [blk*1024 + w*256, +256), 4 rows/lane packed as two <2 x float> pairs
// (v_pk_fma_f32 = the 157 TF fp32 path). Weights are read with uniform
// indices straight from the kernel args -> compiler promotes to s_load
// (SGPR broadcast, no LDS/RF-fanout cost). LDS only for Cost/Pmax/cumprev
// and the per-wave td exchange. Both __syncthreads happen BEFORE any global
// store is outstanding, so the vmcnt(0)-before-barrier drain never stalls
// the store stream; stores then flow uninterrupted to the 6.5 TB/s ceiling.

typedef float f2 __attribute__((ext_vector_type(2)));

#define NBLOCKS 256

// LDS float offsets
#define OFF_CS 0     // Cost[100]
#define OFF_PM 128   // Pmax[100]   (16B-aligned base)
#define OFF_CP 256   // cumprev[100]
#define OFF_TD 384   // tdbuf[4 waves][256 rows]
#define SMEM_FLOATS (OFF_TD + 1024)

__device__ __forceinline__ f2 splat(float v) { return (f2){v, v}; }

__global__ __launch_bounds__(256, 1) void e2e_mlp_fused_kernel(
    const float* __restrict__ x,    const float* __restrict__ Cost,
    const float* __restrict__ Pmax, const float* __restrict__ Pd,
    const float* __restrict__ wcapp,const float* __restrict__ W1,
    const float* __restrict__ b1,   const float* __restrict__ W2,
    const float* __restrict__ b2,   const float* __restrict__ W3,
    const float* __restrict__ b3p,  float* __restrict__ out) {
  __shared__ float s[SMEM_FLOATS];
  const int t = threadIdx.x;
  const int lane = t & 63;
  const int w = t >> 6;
  const long wrow = (long)blockIdx.x * 1024 + (long)w * 256;

  // x loads issued first (latency hidden under staging/scalar loads).
  // Slots: pair A = rows (lane, lane+64), pair B = rows (lane+128, lane+192).
  const float4* __restrict__ x4 = (const float4*)x;
  const float4 xA0 = x4[wrow + lane];
  const float4 xA1 = x4[wrow + 64 + lane];
  const float4 xB0 = x4[wrow + 128 + lane];
  const float4 xB1 = x4[wrow + 192 + lane];

  if (t < 100) {
    s[OFF_CS + t] = Cost[t];
    s[OFF_PM + t] = Pmax[t];
  }

  // per-wave sum(Pd): lanes 0..24 load float4, shuffle-reduce, broadcast.
  float p = 0.0f;
  if (lane < 25) {
    const float4 q = ((const float4*)Pd)[lane];
    p = q.x + q.y + q.z + q.w;
  }
#pragma unroll
  for (int off = 32; off; off >>= 1) p += __shfl_down(p, off, 64);
  const float spd = __shfl(p, 0, 64);

  __syncthreads();  // B0: Cost/Pmax staged (no global stores outstanding)

  // cumprev via O(N^2) rank-sum (stable tie-break == jnp stable argsort)
  if (t < 100) {
    const float c = s[OFF_CS + t];
    float acc = 0.0f;
    for (int i = 0; i < 100; ++i) {
      const float ci = s[OFF_CS + i];
      acc += ((ci < c) || (ci == c && i < t)) ? s[OFF_PM + i] : 0.0f;
    }
    s[OFF_CP + t] = acc;
  }

  // ---- MLP: layer 1 (weights via scalar loads, uniform indices) ----
  const f2 zero = {0.0f, 0.0f};
  const f2 Ax = {xA0.x, xA1.x}, Ay = {xA0.y, xA1.y};
  const f2 Az = {xA0.z, xA1.z}, Aw = {xA0.w, xA1.w};
  const f2 Bx = {xB0.x, xB1.x}, By = {xB0.y, xB1.y};
  const f2 Bz = {xB0.z, xB1.z}, Bw = {xB0.w, xB1.w};

  f2 h1a[30], h1b[30];
#pragma unroll 3
  for (int k = 0; k < 30; ++k) {
    const float w0 = W1[k], w1 = W1[30 + k], w2c = W1[60 + k], w3c = W1[90 + k];
    const float bb = b1[k];
    f2 pa = splat(bb), pb = splat(bb);
    pa = __builtin_elementwise_fma(Ax, splat(w0), pa);
    pb = __builtin_elementwise_fma(Bx, splat(w0), pb);
    pa = __builtin_elementwise_fma(Ay, splat(w1), pa);
    pb = __builtin_elementwise_fma(By, splat(w1), pb);
    pa = __builtin_elementwise_fma(Az, splat(w2c), pa);
    pb = __builtin_elementwise_fma(Bz, splat(w2c), pb);
    pa = __builtin_elementwise_fma(Aw, splat(w3c), pa);
    pb = __builtin_elementwise_fma(Bw, splat(w3c), pb);
    h1a[k] = __builtin_elementwise_max(pa, zero);
    h1b[k] = __builtin_elementwise_max(pb, zero);
  }

  // ---- layer 2 + output layer (W2 column k via scalar loads) ----
  // unroll 2 -> 4 independent FMA chains (hides 4-cyc dep latency) and
  // bounded SGPR live range (~60 weight SGPRs/group < 102 budget).
  f2 yA = zero, yB = zero;
#pragma unroll 2
  for (int k = 0; k < 30; ++k) {
    const float b2k = b2[k], w3k = W3[k];
    f2 sa = splat(b2k), sb = splat(b2k);
#pragma unroll
    for (int i = 0; i < 30; ++i) {
      const f2 wv = splat(W2[i * 30 + k]);
      sa = __builtin_elementwise_fma(h1a[i], wv, sa);
      sb = __builtin_elementwise_fma(h1b[i], wv, sb);
    }
    sa = __builtin_elementwise_max(sa, zero);
    sb = __builtin_elementwise_max(sb, zero);
    yA = __builtin_elementwise_fma(sa, splat(w3k), yA);
    yB = __builtin_elementwise_fma(sb, splat(w3k), yB);
  }

  // total_d = sum(Pd) - wc*(y + b3)
  const float wc = wcapp[0];
  const float Aconst = spd - wc * b3p[0];
  {
    float* __restrict__ tdb = &s[OFF_TD + w * 256];
    tdb[lane]       = Aconst - wc * yA.x;
    tdb[lane + 64]  = Aconst - wc * yA.y;
    tdb[lane + 128] = Aconst - wc * yB.x;
    tdb[lane + 192] = Aconst - wc * yB.y;
  }

  __syncthreads();  // B1: cumprev + tdbuf visible; still no stores outstanding

  // ---- store phase: 50 lanes/wave, 2 rows (800 B contiguous) per inst ----
  if (lane < 50) {
    const int g = lane % 25;        // fixed column group -> cpr/pmx in regs
    const int half = lane / 25;     // row parity
    const float4 cpr = *(const float4*)&s[OFF_CP + g * 4];
    const float4 pmx = *(const float4*)&s[OFF_PM + g * 4];
    const float* __restrict__ tdr = &s[OFF_TD + w * 256 + half];
    float* __restrict__ op = out + (wrow + half) * 100 + g * 4;
#pragma unroll 4
    for (int it = 0; it < 128; ++it) {
      const float td = tdr[2 * it];
      float4 v;
      v.x = fminf(fmaxf(td - cpr.x, 0.0f), pmx.x);
      v.y = fminf(fmaxf(td - cpr.y, 0.0f), pmx.y);
      v.z = fminf(fmaxf(td - cpr.z, 0.0f), pmx.z);
      v.w = fminf(fmaxf(td - cpr.w, 0.0f), pmx.w);
      *(float4*)op = v;
      op += 200;  // 2 rows
    }
  }
}

extern "C" void kernel_launch(void* const* d_in, const int* in_sizes, int n_in,
                              void* d_out, int out_size, void* d_ws, size_t ws_size,
                              hipStream_t stream) {
  const float* x    = (const float*)d_in[0];
  const float* Cost = (const float*)d_in[1];
  const float* Pmax = (const float*)d_in[2];
  const float* Pd   = (const float*)d_in[3];
  const float* wcap = (const float*)d_in[4];
  const float* W1   = (const float*)d_in[5];
  const float* b1   = (const float*)d_in[6];
  const float* W2   = (const float*)d_in[7];
  const float* b2   = (const float*)d_in[8];
  const float* W3   = (const float*)d_in[9];
  const float* b3   = (const float*)d_in[10];
  float* out = (float*)d_out;

  e2e_mlp_fused_kernel<<<NBLOCKS, 256, 0, stream>>>(
      x, Cost, Pmax, Pd, wcap, W1, b1, W2, b2, W3, b3, out);
}

// Round 4
// 150.740 us; speedup vs baseline: 1.0181x; 1.0181x over previous
//
#include <hip/hip_runtime.h>
#include <hip/hip_bf16.h>

// Round-2 MLP (LDS-broadcast weights, packed fp32, 4 rows/lane) + full-line
// store phase. Key insight from round-3 profile: WRITE_SIZE was 1.30x ideal
// (= 4.0625 lines * 128B per 400B row): row-granular stores dirty each
// 128B boundary line from two instructions and L2 writes back full lines
// without merging. Fix: each wave stores its 256-row chunk (102,400 B,
// 1024B-aligned) as 100 full-wave 64x16B stores -> every line written
// exactly once -> WRITE_SIZE = 102,400 KB, drain 20.5us -> 15.7us.

typedef float f2 __attribute__((ext_vector_type(2)));
typedef float f4 __attribute__((ext_vector_type(4)));

#define NBLOCKS 256

// LDS float offsets
#define OFF_W2 0      // [k*32+i]=W2[i][k] i<30; +30=b2[k]; +31=W3[k]  (960)
#define OFF_W1 960    // [k*8+i]=W1[i][k] i<4; +4=b1[k]; pads 0        (240)
#define OFF_CP 1200   // cumprev[100] (16B-aligned)
#define OFF_PM 1328   // Pmax[100]    (16B-aligned)
#define OFF_CS 1456   // Cost[100]
#define OFF_TD 1568   // tdbuf[4 waves][256 rows]
#define SMEM_FLOATS (OFF_TD + 1024)

__device__ __forceinline__ f2 splat2(float v) { return (f2){v, v}; }

__global__ __launch_bounds__(256, 1) void e2e_mlp_fused_kernel(
    const float* __restrict__ x,    const float* __restrict__ Cost,
    const float* __restrict__ Pmax, const float* __restrict__ Pd,
    const float* __restrict__ wcapp,const float* __restrict__ W1,
    const float* __restrict__ b1,   const float* __restrict__ W2,
    const float* __restrict__ b2,   const float* __restrict__ W3,
    const float* __restrict__ b3p,  float* __restrict__ out) {
  __shared__ float s[SMEM_FLOATS];
  const int t = threadIdx.x;
  const int lane = t & 63;
  const int w = t >> 6;
  const long wrow = (long)blockIdx.x * 1024 + (long)w * 256;

  // x loads first (latency hidden under staging).
  const float4* __restrict__ x4 = (const float4*)x;
  const float4 xA0 = x4[wrow + lane];
  const float4 xA1 = x4[wrow + 64 + lane];
  const float4 xB0 = x4[wrow + 128 + lane];
  const float4 xB1 = x4[wrow + 192 + lane];

  // ---- stage weights (transposed+padded), Cost/Pmax ----
  for (int idx = t; idx < 960; idx += 256) {
    const int k = idx >> 5, i = idx & 31;
    float v;
    if (i < 30)       v = W2[i * 30 + k];
    else if (i == 30) v = b2[k];
    else              v = W3[k];
    s[OFF_W2 + idx] = v;
  }
  if (t < 240) {
    const int k = t >> 3, i = t & 7;
    float v = 0.0f;
    if (i < 4)       v = W1[i * 30 + k];
    else if (i == 4) v = b1[k];
    s[OFF_W1 + t] = v;
  }
  if (t < 100) {
    s[OFF_CS + t] = Cost[t];
    s[OFF_PM + t] = Pmax[t];
  }

  // per-wave sum(Pd): lanes 0..24 load float4, shuffle-reduce, broadcast.
  float p = 0.0f;
  if (lane < 25) {
    const float4 q = ((const float4*)Pd)[lane];
    p = q.x + q.y + q.z + q.w;
  }
#pragma unroll
  for (int off = 32; off; off >>= 1) p += __shfl_down(p, off, 64);
  const float spd = __shfl(p, 0, 64);

  __syncthreads();  // B0: staging visible (no global stores outstanding)

  // cumprev via O(N^2) rank-sum (stable tie-break == jnp stable argsort)
  if (t < 100) {
    const float c = s[OFF_CS + t];
    float acc = 0.0f;
    for (int i = 0; i < 100; ++i) {
      const float ci = s[OFF_CS + i];
      acc += ((ci < c) || (ci == c && i < t)) ? s[OFF_PM + i] : 0.0f;
    }
    s[OFF_CP + t] = acc;
  }

  // ---- MLP layer 1 (packed f2: pair A = rows lane/lane+64, B = +128/+192) --
  const f2 zero = {0.0f, 0.0f};
  const f2 Ax = {xA0.x, xA1.x}, Ay = {xA0.y, xA1.y};
  const f2 Az = {xA0.z, xA1.z}, Aw = {xA0.w, xA1.w};
  const f2 Bx = {xB0.x, xB1.x}, By = {xB0.y, xB1.y};
  const f2 Bz = {xB0.z, xB1.z}, Bw = {xB0.w, xB1.w};

  f2 h1a[30], h1b[30];
#pragma unroll
  for (int k = 0; k < 30; ++k) {
    const float4 wv = *(const float4*)&s[OFF_W1 + k * 8];
    const float bb = s[OFF_W1 + k * 8 + 4];
    f2 pa = splat2(bb), pb = splat2(bb);
    pa = __builtin_elementwise_fma(Ax, splat2(wv.x), pa);
    pb = __builtin_elementwise_fma(Bx, splat2(wv.x), pb);
    pa = __builtin_elementwise_fma(Ay, splat2(wv.y), pa);
    pb = __builtin_elementwise_fma(By, splat2(wv.y), pb);
    pa = __builtin_elementwise_fma(Az, splat2(wv.z), pa);
    pb = __builtin_elementwise_fma(Bz, splat2(wv.z), pb);
    pa = __builtin_elementwise_fma(Aw, splat2(wv.w), pa);
    pb = __builtin_elementwise_fma(Bw, splat2(wv.w), pb);
    h1a[k] = __builtin_elementwise_max(pa, zero);
    h1b[k] = __builtin_elementwise_max(pb, zero);
  }

  // ---- layer 2 + output (W2 column k via LDS b128 broadcasts) ----
  f2 yA = zero, yB = zero;
#pragma unroll 2
  for (int k = 0; k < 30; ++k) {
    const float4* __restrict__ wr = (const float4*)&s[OFF_W2 + k * 32];
    f2 sa = zero, sb = zero, sa2 = zero, sb2 = zero;
#pragma unroll
    for (int c = 0; c < 7; ++c) {
      const float4 wv = wr[c];
      sa  = __builtin_elementwise_fma(h1a[4 * c],     splat2(wv.x), sa);
      sb  = __builtin_elementwise_fma(h1b[4 * c],     splat2(wv.x), sb);
      sa2 = __builtin_elementwise_fma(h1a[4 * c + 1], splat2(wv.y), sa2);
      sb2 = __builtin_elementwise_fma(h1b[4 * c + 1], splat2(wv.y), sb2);
      sa  = __builtin_elementwise_fma(h1a[4 * c + 2], splat2(wv.z), sa);
      sb  = __builtin_elementwise_fma(h1b[4 * c + 2], splat2(wv.z), sb);
      sa2 = __builtin_elementwise_fma(h1a[4 * c + 3], splat2(wv.w), sa2);
      sb2 = __builtin_elementwise_fma(h1b[4 * c + 3], splat2(wv.w), sb2);
    }
    const float4 w7 = wr[7];  // {W2[28][k], W2[29][k], b2[k], W3[k]}
    sa  = __builtin_elementwise_fma(h1a[28], splat2(w7.x), sa);
    sb  = __builtin_elementwise_fma(h1b[28], splat2(w7.x), sb);
    sa2 = __builtin_elementwise_fma(h1a[29], splat2(w7.y), sa2);
    sb2 = __builtin_elementwise_fma(h1b[29], splat2(w7.y), sb2);
    f2 hA = __builtin_elementwise_max(sa + sa2 + splat2(w7.z), zero);
    f2 hB = __builtin_elementwise_max(sb + sb2 + splat2(w7.z), zero);
    yA = __builtin_elementwise_fma(hA, splat2(w7.w), yA);
    yB = __builtin_elementwise_fma(hB, splat2(w7.w), yB);
  }

  // total_d = sum(Pd) - wc*(y + b3) -> wave-private LDS exchange
  const float wc = wcapp[0];
  const float Aconst = spd - wc * b3p[0];
  {
    float* __restrict__ tdb = &s[OFF_TD + w * 256];
    tdb[lane]       = Aconst - wc * yA.x;
    tdb[lane + 64]  = Aconst - wc * yA.y;
    tdb[lane + 128] = Aconst - wc * yB.x;
    tdb[lane + 192] = Aconst - wc * yB.y;
  }

  __syncthreads();  // B1: cumprev visible (tdbuf is wave-private anyway)

  // ---- store phase: full-line coverage ----
  // Wave chunk = bytes [wrow*400, +102400), 1024B-aligned. Iteration it:
  // lane writes bytes [it*1024 + lane*16, +16). row = o/400, colgroup = (o%400)/16.
  {
    const float* __restrict__ tdb = &s[OFF_TD + w * 256];
    const int o0 = lane * 16;
    int r = o0 / 400;            // 0..2
    int m = o0 - 400 * r;        // o mod 400
    float* __restrict__ op = out + wrow * 100 + lane * 4;
#pragma unroll 4
    for (int it = 0; it < 100; ++it) {
      const float td = tdb[r];
      const int c16 = m >> 4;    // 0..24
      const f4 cpr = *(const f4*)&s[OFF_CP + 4 * c16];
      const f4 pmx = *(const f4*)&s[OFF_PM + 4 * c16];
      f4 v = (f4){td, td, td, td} - cpr;
      v = __builtin_elementwise_max(v, (f4){0.0f, 0.0f, 0.0f, 0.0f});
      v = __builtin_elementwise_min(v, pmx);
      *(f4*)op = v;
      op += 256;                 // +1024 B
      m += 224;                  // 1024 mod 400
      r += 2;
      if (m >= 400) { m -= 400; r += 1; }
    }
  }
}

extern "C" void kernel_launch(void* const* d_in, const int* in_sizes, int n_in,
                              void* d_out, int out_size, void* d_ws, size_t ws_size,
                              hipStream_t stream) {
  const float* x    = (const float*)d_in[0];
  const float* Cost = (const float*)d_in[1];
  const float* Pmax = (const float*)d_in[2];
  const float* Pd   = (const float*)d_in[3];
  const float* wcap = (const float*)d_in[4];
  const float* W1   = (const float*)d_in[5];
  const float* b1   = (const float*)d_in[6];
  const float* W2   = (const float*)d_in[7];
  const float* b2   = (const float*)d_in[8];
  const float* W3   = (const float*)d_in[9];
  const float* b3   = (const float*)d_in[10];
  float* out = (float*)d_out;

  e2e_mlp_fused_kernel<<<NBLOCKS, 256, 0, stream>>>(
      x, Cost, Pmax, Pd, wcap, W1, b1, W2, b2, W3, b3, out);
}